// Round 8
// baseline (157.319 us; speedup 1.0000x reference)
//
#include <hip/hip_runtime.h>
#include <math.h>

#define SLOPE  0.2f
#define NB     32
#define LEN    512
#define LATENT 64
#define HID    64
#define IN_DIM 129
#define TROWS  514
#define NTOT   (NB * LEN)      // 16384

typedef __attribute__((ext_vector_type(8)))  short bf16x8;
typedef __attribute__((ext_vector_type(16))) float f32x16;
typedef __attribute__((ext_vector_type(4)))  float f32x4;

struct alignas(8) US4 { unsigned short x, y, z, w; };

// round-to-nearest bf16 split: v = hi + lo + O(2^-18 v)
__device__ inline void bsplit(float v, unsigned short& hi, unsigned short& lo) {
    unsigned int u  = __builtin_bit_cast(unsigned int, v);
    unsigned int hb = (u + 0x7fffu + ((u >> 16) & 1u)) >> 16;
    hi = (unsigned short)hb;
    float fh = __builtin_bit_cast(float, hb << 16);
    float r  = v - fh;                      // exact (Sterbenz)
    unsigned int u2 = __builtin_bit_cast(unsigned int, r);
    lo = (unsigned short)((u2 + 0x7fffu + ((u2 >> 16) & 1u)) >> 16);
}

// pre-pass: W1[:, :, :128] -> fragment-major bf16 hi/lo W1f[l][i][ks][part][lane][8]
//           W1[:, :, 128]  -> W1t fp32 ; also zero out_lad   (ws use: 2.02 MB, proven)
__global__ __launch_bounds__(256)
void conv_w1(const float* __restrict__ W1g, unsigned short* __restrict__ W1f,
             float* __restrict__ W1t, float* __restrict__ out_lad) {
    const int idx = blockIdx.x * 256 + threadIdx.x;   // 0..65535
    if (idx < NTOT) out_lad[idx] = 0.f;
    const int row  = idx >> 4;                        // 0..4095 = l*64 + h
    const int o    = idx & 15;                        // k-octet, k = 8*o
    const int ks   = o >> 1, hi32 = o & 1;
    const int l    = row >> 6, h = row & 63;
    const int i    = h >> 5,  r32 = h & 31;
    const int lane = hi32 * 32 + r32;
    const float* src = W1g + (size_t)row * IN_DIM + o * 8;
    unsigned short hh[8], ll[8];
    #pragma unroll
    for (int e = 0; e < 8; ++e) bsplit(src[e], hh[e], ll[e]);
    // strides (ushorts): l=16384, i=8192, ks=1024, part=512, lane=8
    const size_t base = (size_t)l * 16384 + (size_t)i * 8192 + (size_t)ks * 1024
                      + (size_t)lane * 8;
    *reinterpret_cast<US4*>(W1f + base)       = US4{hh[0], hh[1], hh[2], hh[3]};
    *reinterpret_cast<US4*>(W1f + base + 4)   = US4{hh[4], hh[5], hh[6], hh[7]};
    *reinterpret_cast<US4*>(W1f + base + 512) = US4{ll[0], ll[1], ll[2], ll[3]};
    *reinterpret_cast<US4*>(W1f + base + 516) = US4{ll[4], ll[5], ll[6], ll[7]};
    if (o == 15) W1t[row] = src[8];               // element k=128
}

// 512 threads = 8 waves = 8 latents; each block does 4 n-tiles (half a batch row).
// grid 512 = 2 blocks/CU. A = W1 fragments (L2), B = x (LDS).
__global__ __launch_bounds__(512, 2)
void fused_mfma(const float* __restrict__ xg,
                const float* __restrict__ b1g, const float* __restrict__ W2g,
                const float* __restrict__ b2g,
                const unsigned short* __restrict__ W1f,
                const float* __restrict__ W1t,
                float* __restrict__ out_res, float* __restrict__ out_lad)
{
    __shared__ unsigned short sXh[66][72];   // x hi, stride 144B (16B-aligned)
    __shared__ unsigned short sXl[66][72];   // x lo
    __shared__ float sXt[66][8];             // fp32 xt columns (8 l's)
    __shared__ float sJ[64][8];              // per-l jacobians
    __shared__ float sR[64][8];              // per-l residuals (for coalesced store)

    const int tid  = threadIdx.x;
    const int by   = blockIdx.x & 7;         // latent oct (same-by -> same XCD)
    const int ht   = blockIdx.x >> 3;        // 0..63
    const int pt   = ht >> 1;                // batch row 0..31
    const int s0   = (ht & 1) * 4;           // first of 4 tiles
    const int wn   = tid >> 6;               // 0..7 : which latent
    const int lane = tid & 63;
    const int r32  = lane & 31;
    const int hi32 = lane >> 5;
    const int l    = by * 8 + wn;

    const unsigned short* A0 = W1f + (size_t)l * 16384 + (size_t)lane * 8;

    #pragma unroll 1
    for (int s = s0; s < s0 + 4; ++s) {
        const size_t xrow0 = (size_t)pt * TROWS + s * 64;

        // ---- stage x tile: 66 rows x 64, bf16 hi/lo + fp32 xt columns ----
        for (int i = tid; i < 66 * 16; i += 512) {
            const int row = i >> 4, c4 = (i & 15) << 2;
            const float4 v = *reinterpret_cast<const float4*>(
                xg + (xrow0 + row) * LATENT + c4);
            unsigned short h0,h1,h2,h3, l0,l1,l2,l3;
            bsplit(v.x, h0, l0); bsplit(v.y, h1, l1);
            bsplit(v.z, h2, l2); bsplit(v.w, h3, l3);
            *reinterpret_cast<US4*>(&sXh[row][c4]) = US4{h0, h1, h2, h3};
            *reinterpret_cast<US4*>(&sXl[row][c4]) = US4{l0, l1, l2, l3};
        }
        for (int i = tid; i < 66 * 8; i += 512) {
            const int row = i >> 3, w = i & 7;
            sXt[row][w] = xg[(xrow0 + row) * LATENT + by * 8 + w];
        }
        __syncthreads();   // B1: x tile visible

        // ---- acc init = b1 (C/D row h = i*32 + 4*hi32 + 8*g + m) ----
        f32x16 acc[2][2];
        #pragma unroll
        for (int i = 0; i < 2; ++i)
            #pragma unroll
            for (int g = 0; g < 4; ++g) {
                const f32x4 b14 = *reinterpret_cast<const f32x4*>(
                    b1g + l * HID + i * 32 + hi32 * 4 + g * 8);
                #pragma unroll
                for (int m = 0; m < 4; ++m) {
                    acc[i][0][g * 4 + m] = b14[m];
                    acc[i][1][g * 4 + m] = b14[m];
                }
            }

        // ---- K loop: A = W1 fragments (L2-resident), B = x rows (LDS) ----
        #pragma unroll
        for (int ks = 0; ks < 8; ++ks) {
            const int lag = ks >> 2;
            const int cc  = (ks & 3) * 16 + hi32 * 8;
            const unsigned short* p0 = A0 + ks * 1024;
            bf16x8 awh[2], awl[2], bxh[2], bxl[2];
            #pragma unroll
            for (int i = 0; i < 2; ++i) {
                awh[i] = *reinterpret_cast<const bf16x8*>(p0 + i * 8192);
                awl[i] = *reinterpret_cast<const bf16x8*>(p0 + i * 8192 + 512);
            }
            #pragma unroll
            for (int j = 0; j < 2; ++j) {
                const int rr = j * 32 + r32 + lag;
                bxh[j] = *reinterpret_cast<const bf16x8*>(&sXh[rr][cc]);
                bxl[j] = *reinterpret_cast<const bf16x8*>(&sXl[rr][cc]);
            }
            #pragma unroll
            for (int i = 0; i < 2; ++i)
                #pragma unroll
                for (int j = 0; j < 2; ++j) {
                    acc[i][j] = __builtin_amdgcn_mfma_f32_32x32x16_bf16(awh[i], bxh[j], acc[i][j], 0, 0, 0);
                    acc[i][j] = __builtin_amdgcn_mfma_f32_32x32x16_bf16(awh[i], bxl[j], acc[i][j], 0, 0, 0);
                    acc[i][j] = __builtin_amdgcn_mfma_f32_32x32x16_bf16(awl[i], bxh[j], acc[i][j], 0, 0, 0);
                }
        }

        // ---- fused epilogue: h in (i, reg, hi32); n = j*32 + r32 ----
        const float xt0 = sXt[r32 + 2][wn];
        const float xt1 = sXt[32 + r32 + 2][wn];
        float res0 = 0.f, res1 = 0.f, jp0 = 0.f, jp1 = 0.f, jc = 0.f;

        #pragma unroll
        for (int i = 0; i < 2; ++i)
            #pragma unroll
            for (int g = 0; g < 4; ++g) {
                const int h0 = l * HID + i * 32 + hi32 * 4 + g * 8;
                const f32x4 wt = *reinterpret_cast<const f32x4*>(W1t + h0);
                const f32x4 w2 = *reinterpret_cast<const f32x4*>(W2g + h0);
                #pragma unroll
                for (int m = 0; m < 4; ++m) {
                    const float c0 = w2[m] * wt[m];
                    jc += c0;
                    const int r = g * 4 + m;
                    const float pre0 = fmaf(xt0, wt[m], acc[i][0][r]);
                    const float pre1 = fmaf(xt1, wt[m], acc[i][1][r]);
                    res0 += w2[m] * fmaxf(pre0, SLOPE * pre0);
                    res1 += w2[m] * fmaxf(pre1, SLOPE * pre1);
                    jp0 += (pre0 >= 0.f) ? c0 : 0.f;
                    jp1 += (pre1 >= 0.f) ? c0 : 0.f;
                }
            }

        res0 += __shfl_xor(res0, 32);
        res1 += __shfl_xor(res1, 32);
        jp0  += __shfl_xor(jp0, 32);
        jp1  += __shfl_xor(jp1, 32);
        jc   += __shfl_xor(jc, 32);

        if (hi32 == 0) {
            const float b2v = b2g[l];
            sR[r32][wn]      = res0 + b2v;
            sR[r32 + 32][wn] = res1 + b2v;
            sJ[r32][wn]      = SLOPE * jc + (1.f - SLOPE) * jp0;
            sJ[r32 + 32][wn] = SLOPE * jc + (1.f - SLOPE) * jp1;
        }
        __syncthreads();   // B2: sR/sJ visible

        const size_t nbase = (size_t)pt * LEN + s * 64;
        if (tid < 128) {   // coalesced residual store: 32B per n, float4 lanes
            const int n = tid >> 1, part = (tid & 1) * 4;
            *reinterpret_cast<f32x4*>(out_res + (nbase + n) * LATENT + by * 8 + part) =
                *reinterpret_cast<const f32x4*>(&sR[n][part]);
        } else if (tid >= 448) {   // wave 7: logabsdet partial
            const int n = tid - 448;
            const float p = sJ[n][0] * sJ[n][1] * sJ[n][2] * sJ[n][3]
                          * sJ[n][4] * sJ[n][5] * sJ[n][6] * sJ[n][7];
            atomicAdd(&out_lad[nbase + n], logf(fabsf(p)));
        }
        __syncthreads();   // B3: LDS free for next tile
    }
}

extern "C" void kernel_launch(void* const* d_in, const int* in_sizes, int n_in,
                              void* d_out, int out_size, void* d_ws, size_t ws_size,
                              hipStream_t stream) {
    const float* xg  = (const float*)d_in[0];
    const float* W1g = (const float*)d_in[1];
    const float* b1g = (const float*)d_in[2];
    const float* W2g = (const float*)d_in[3];
    const float* b2g = (const float*)d_in[4];

    float* out_res = (float*)d_out;
    float* out_lad = out_res + (size_t)NTOT * LATENT;

    float*          W1t = (float*)d_ws;                   // 16 KB
    unsigned short* W1f = (unsigned short*)(W1t + 4096);  // 2 MB fragment-major

    conv_w1<<<256, 256, 0, stream>>>(W1g, W1f, W1t, out_lad);

    dim3 grid(512);  // (8 latent octs) x (32 batch rows) x (2 halves) = 2 blocks/CU
    fused_mfma<<<grid, 512, 0, stream>>>(xg, b1g, W2g, b2g, W1f, W1t,
                                         out_res, out_lad);
}

// Round 9
// 151.701 us; speedup vs baseline: 1.0370x; 1.0370x over previous
//
#include <hip/hip_runtime.h>
#include <math.h>

#define SLOPE  0.2f
#define NB     32
#define LEN    512
#define LATENT 64
#define HID    64
#define IN_DIM 129
#define TROWS  514
#define NTOT   (NB * LEN)      // 16384

typedef __attribute__((ext_vector_type(8)))  short bf16x8;
typedef __attribute__((ext_vector_type(16))) float f32x16;
typedef __attribute__((ext_vector_type(4)))  float f32x4;

struct alignas(8) US4 { unsigned short x, y, z, w; };

// round-to-nearest bf16 split: v = hi + lo + O(2^-18 v)
__device__ inline void bsplit(float v, unsigned short& hi, unsigned short& lo) {
    unsigned int u  = __builtin_bit_cast(unsigned int, v);
    unsigned int hb = (u + 0x7fffu + ((u >> 16) & 1u)) >> 16;
    hi = (unsigned short)hb;
    float fh = __builtin_bit_cast(float, hb << 16);
    float r  = v - fh;                      // exact (Sterbenz)
    unsigned int u2 = __builtin_bit_cast(unsigned int, r);
    lo = (unsigned short)((u2 + 0x7fffu + ((u2 >> 16) & 1u)) >> 16);
}

// pre-pass: W1[:, :, :128] -> fragment-major bf16 hi/lo W1f[l][i][ks][part][lane][8]
//           W1[:, :, 128]  -> W1t fp32 ; also zero out_lad   (ws use: 2.02 MB, proven)
__global__ __launch_bounds__(256)
void conv_w1(const float* __restrict__ W1g, unsigned short* __restrict__ W1f,
             float* __restrict__ W1t, float* __restrict__ out_lad) {
    const int idx = blockIdx.x * 256 + threadIdx.x;   // 0..65535
    if (idx < NTOT) out_lad[idx] = 0.f;
    const int row  = idx >> 4;                        // 0..4095 = l*64 + h
    const int o    = idx & 15;                        // k-octet, k = 8*o
    const int ks   = o >> 1, hi32 = o & 1;
    const int l    = row >> 6, h = row & 63;
    const int i    = h >> 5,  r32 = h & 31;
    const int lane = hi32 * 32 + r32;
    const float* src = W1g + (size_t)row * IN_DIM + o * 8;
    unsigned short hh[8], ll[8];
    #pragma unroll
    for (int e = 0; e < 8; ++e) bsplit(src[e], hh[e], ll[e]);
    // strides (ushorts): l=16384, i=8192, ks=1024, part=512, lane=8
    const size_t base = (size_t)l * 16384 + (size_t)i * 8192 + (size_t)ks * 1024
                      + (size_t)lane * 8;
    *reinterpret_cast<US4*>(W1f + base)       = US4{hh[0], hh[1], hh[2], hh[3]};
    *reinterpret_cast<US4*>(W1f + base + 4)   = US4{hh[4], hh[5], hh[6], hh[7]};
    *reinterpret_cast<US4*>(W1f + base + 512) = US4{ll[0], ll[1], ll[2], ll[3]};
    *reinterpret_cast<US4*>(W1f + base + 516) = US4{ll[4], ll[5], ll[6], ll[7]};
    if (o == 15) W1t[row] = src[8];               // element k=128
}

// 256 threads = 4 waves = 4 latents; W1 fragments register-resident (needs the
// 256-reg cap of (256,2)); each block loops the 8 n-tiles of one batch row.
// grid 512 = 2 blocks/CU; bid&7 = batch-row group -> per-XCD x locality.
__global__ __launch_bounds__(256, 2)
void fused_mfma(const float* __restrict__ xg,
                const float* __restrict__ b1g, const float* __restrict__ W2g,
                const float* __restrict__ b2g,
                const unsigned short* __restrict__ W1f,
                const float* __restrict__ W1t,
                float* __restrict__ out_res, float* __restrict__ out_lad)
{
    __shared__ unsigned short sXh[66][72];   // x hi, stride 144B (16B-aligned)
    __shared__ unsigned short sXl[66][72];   // x lo
    __shared__ float sXt[66][4];             // fp32 xt columns (4 l's)
    __shared__ float sJ[64][4];              // per-l jacobians

    const int tid  = threadIdx.x;
    const int xcd  = blockIdx.x & 7;
    const int k    = blockIdx.x >> 3;        // 0..63
    const int pt   = xcd * 4 + (k & 3);      // batch row 0..31
    const int quad = k >> 2;                 // latent quad 0..15
    const int wn   = tid >> 6;               // 0..3 : which latent
    const int lane = tid & 63;
    const int r32  = lane & 31;
    const int hi32 = lane >> 5;
    const int l    = quad * 4 + wn;

    // ---- load W1 fragments ONCE into registers (32 x bf16x8 = 128 VGPR) ----
    const unsigned short* A0 = W1f + (size_t)l * 16384 + (size_t)lane * 8;
    bf16x8 awh[2][8], awl[2][8];
    #pragma unroll
    for (int i = 0; i < 2; ++i)
        #pragma unroll
        for (int ks = 0; ks < 8; ++ks) {
            const unsigned short* p = A0 + i * 8192 + ks * 1024;
            awh[i][ks] = *reinterpret_cast<const bf16x8*>(p);
            awl[i][ks] = *reinterpret_cast<const bf16x8*>(p + 512);
        }

    // epilogue constants (register-resident, tile-invariant)
    float w1t[2][4][4], w2c[2][4][4], b1c[2][4][4];
    #pragma unroll
    for (int i = 0; i < 2; ++i)
        #pragma unroll
        for (int g = 0; g < 4; ++g) {
            const int h0 = l * HID + i * 32 + hi32 * 4 + g * 8;
            *reinterpret_cast<f32x4*>(w1t[i][g]) = *reinterpret_cast<const f32x4*>(W1t + h0);
            *reinterpret_cast<f32x4*>(w2c[i][g]) = *reinterpret_cast<const f32x4*>(W2g + h0);
            *reinterpret_cast<f32x4*>(b1c[i][g]) = *reinterpret_cast<const f32x4*>(b1g + h0);
        }
    const float b2v = b2g[l];

    #pragma unroll 1
    for (int s = 0; s < 8; ++s) {
        const size_t xrow0 = (size_t)pt * TROWS + s * 64;

        // ---- stage x tile: 66 rows x 64, bf16 hi/lo + fp32 xt columns ----
        for (int i = tid; i < 66 * 16; i += 256) {
            const int row = i >> 4, c4 = (i & 15) << 2;
            const float4 v = *reinterpret_cast<const float4*>(
                xg + (xrow0 + row) * LATENT + c4);
            unsigned short h0,h1,h2,h3, l0,l1,l2,l3;
            bsplit(v.x, h0, l0); bsplit(v.y, h1, l1);
            bsplit(v.z, h2, l2); bsplit(v.w, h3, l3);
            *reinterpret_cast<US4*>(&sXh[row][c4]) = US4{h0, h1, h2, h3};
            *reinterpret_cast<US4*>(&sXl[row][c4]) = US4{l0, l1, l2, l3};
        }
        for (int i = tid; i < 66 * 4; i += 256) {
            const int row = i >> 2, w = i & 3;
            sXt[row][w] = xg[(xrow0 + row) * LATENT + quad * 4 + w];
        }
        __syncthreads();   // B1: x tile visible

        // ---- acc init = b1 (C/D row h = i*32 + 4*hi32 + 8*g + m) ----
        f32x16 acc[2][2];
        #pragma unroll
        for (int i = 0; i < 2; ++i)
            #pragma unroll
            for (int g = 0; g < 4; ++g)
                #pragma unroll
                for (int m = 0; m < 4; ++m) {
                    acc[i][0][g * 4 + m] = b1c[i][g][m];
                    acc[i][1][g * 4 + m] = b1c[i][g][m];
                }

        // ---- K loop: A = registers, B = x rows (LDS) — no global loads ----
        #pragma unroll
        for (int ks = 0; ks < 8; ++ks) {
            const int lag = ks >> 2;
            const int cc  = (ks & 3) * 16 + hi32 * 8;
            bf16x8 bxh[2], bxl[2];
            #pragma unroll
            for (int j = 0; j < 2; ++j) {
                const int rr = j * 32 + r32 + lag;
                bxh[j] = *reinterpret_cast<const bf16x8*>(&sXh[rr][cc]);
                bxl[j] = *reinterpret_cast<const bf16x8*>(&sXl[rr][cc]);
            }
            #pragma unroll
            for (int i = 0; i < 2; ++i)
                #pragma unroll
                for (int j = 0; j < 2; ++j) {
                    acc[i][j] = __builtin_amdgcn_mfma_f32_32x32x16_bf16(awh[i][ks], bxh[j], acc[i][j], 0, 0, 0);
                    acc[i][j] = __builtin_amdgcn_mfma_f32_32x32x16_bf16(awh[i][ks], bxl[j], acc[i][j], 0, 0, 0);
                    acc[i][j] = __builtin_amdgcn_mfma_f32_32x32x16_bf16(awl[i][ks], bxh[j], acc[i][j], 0, 0, 0);
                }
        }

        // ---- fused epilogue: h in (i, reg, hi32); n = j*32 + r32 ----
        const float xt0 = sXt[r32 + 2][wn];
        const float xt1 = sXt[32 + r32 + 2][wn];
        float res0 = 0.f, res1 = 0.f, jp0 = 0.f, jp1 = 0.f, jc = 0.f;

        #pragma unroll
        for (int i = 0; i < 2; ++i)
            #pragma unroll
            for (int g = 0; g < 4; ++g)
                #pragma unroll
                for (int m = 0; m < 4; ++m) {
                    const float c0 = w2c[i][g][m] * w1t[i][g][m];
                    jc += c0;
                    const int r = g * 4 + m;
                    const float pre0 = fmaf(xt0, w1t[i][g][m], acc[i][0][r]);
                    const float pre1 = fmaf(xt1, w1t[i][g][m], acc[i][1][r]);
                    res0 += w2c[i][g][m] * fmaxf(pre0, SLOPE * pre0);
                    res1 += w2c[i][g][m] * fmaxf(pre1, SLOPE * pre1);
                    jp0 += (pre0 >= 0.f) ? c0 : 0.f;
                    jp1 += (pre1 >= 0.f) ? c0 : 0.f;
                }

        res0 += __shfl_xor(res0, 32);
        res1 += __shfl_xor(res1, 32);
        jp0  += __shfl_xor(jp0, 32);
        jp1  += __shfl_xor(jp1, 32);
        jc   += __shfl_xor(jc, 32);

        const size_t nbase = (size_t)pt * LEN + s * 64;
        if (hi32 == 0) {
            const size_t n0 = nbase + r32;
            out_res[n0 * LATENT + l]        = res0 + b2v;
            out_res[(n0 + 32) * LATENT + l] = res1 + b2v;
            sJ[r32][wn]      = SLOPE * jc + (1.f - SLOPE) * jp0;
            sJ[r32 + 32][wn] = SLOPE * jc + (1.f - SLOPE) * jp1;
        }
        __syncthreads();   // B2: sJ visible
        if (tid < 64) {
            const float p = sJ[tid][0] * sJ[tid][1] * sJ[tid][2] * sJ[tid][3];
            atomicAdd(&out_lad[nbase + tid], logf(fabsf(p)));
        }
        __syncthreads();   // B3: LDS free for next tile
    }
}

extern "C" void kernel_launch(void* const* d_in, const int* in_sizes, int n_in,
                              void* d_out, int out_size, void* d_ws, size_t ws_size,
                              hipStream_t stream) {
    const float* xg  = (const float*)d_in[0];
    const float* W1g = (const float*)d_in[1];
    const float* b1g = (const float*)d_in[2];
    const float* W2g = (const float*)d_in[3];
    const float* b2g = (const float*)d_in[4];

    float* out_res = (float*)d_out;
    float* out_lad = out_res + (size_t)NTOT * LATENT;

    float*          W1t = (float*)d_ws;                   // 16 KB
    unsigned short* W1f = (unsigned short*)(W1t + 4096);  // 2 MB fragment-major

    conv_w1<<<256, 256, 0, stream>>>(W1g, W1f, W1t, out_lad);

    dim3 grid(512);  // 8 xcd-groups x 4 rows x 16 latent quads = 2 blocks/CU
    fused_mfma<<<grid, 256, 0, stream>>>(xg, b1g, W2g, b2g, W1f, W1t,
                                         out_res, out_lad);
}

// Round 11
// 143.474 us; speedup vs baseline: 1.0965x; 1.0573x over previous
//
#include <hip/hip_runtime.h>
#include <math.h>

#define SLOPE  0.2f
#define NB     32
#define LEN    512
#define LATENT 64
#define HID    64
#define IN_DIM 129
#define TROWS  514
#define NTOT   (NB * LEN)      // 16384

typedef __attribute__((ext_vector_type(8)))  short bf16x8;
typedef __attribute__((ext_vector_type(16))) float f32x16;
typedef __attribute__((ext_vector_type(4)))  float f32x4;

struct alignas(8) US4 { unsigned short x, y, z, w; };

// round-to-nearest bf16 split: v = hi + lo + O(2^-18 v)
__device__ inline void bsplit(float v, unsigned short& hi, unsigned short& lo) {
    unsigned int u  = __builtin_bit_cast(unsigned int, v);
    unsigned int hb = (u + 0x7fffu + ((u >> 16) & 1u)) >> 16;
    hi = (unsigned short)hb;
    float fh = __builtin_bit_cast(float, hb << 16);
    float r  = v - fh;                      // exact (Sterbenz)
    unsigned int u2 = __builtin_bit_cast(unsigned int, r);
    lo = (unsigned short)((u2 + 0x7fffu + ((u2 >> 16) & 1u)) >> 16);
}

// pre-pass (256 blocks! idx<=65535 -> row<=4095, in bounds):
//   W1[:, :, :128] -> fragment-major bf16 hi/lo W1f[l][i][ks][part][lane][8]
//   W1[:, :, 128]  -> W1t fp32 ; zero out_lad   (ws use 2.02 MB, proven)
__global__ __launch_bounds__(256)
void conv_w1(const float* __restrict__ W1g, unsigned short* __restrict__ W1f,
             float* __restrict__ W1t, float* __restrict__ out_lad) {
    const int idx = blockIdx.x * 256 + threadIdx.x;   // 0..65535
    if (idx < NTOT) out_lad[idx] = 0.f;
    const int row  = idx >> 4;                        // 0..4095 = l*64 + h
    const int o    = idx & 15;                        // k-octet, k = 8*o
    const int ks   = o >> 1, hi32 = o & 1;
    const int l    = row >> 6, h = row & 63;
    const int i    = h >> 5,  r32 = h & 31;
    const int lane = hi32 * 32 + r32;
    const float* src = W1g + (size_t)row * IN_DIM + o * 8;
    unsigned short hh[8], ll[8];
    #pragma unroll
    for (int e = 0; e < 8; ++e) bsplit(src[e], hh[e], ll[e]);
    // strides (ushorts): l=16384, i=8192, ks=1024, part=512, lane=8
    const size_t base = (size_t)l * 16384 + (size_t)i * 8192 + (size_t)ks * 1024
                      + (size_t)lane * 8;
    *reinterpret_cast<US4*>(W1f + base)       = US4{hh[0], hh[1], hh[2], hh[3]};
    *reinterpret_cast<US4*>(W1f + base + 4)   = US4{hh[4], hh[5], hh[6], hh[7]};
    *reinterpret_cast<US4*>(W1f + base + 512) = US4{ll[0], ll[1], ll[2], ll[3]};
    *reinterpret_cast<US4*>(W1f + base + 516) = US4{ll[4], ll[5], ll[6], ll[7]};
    if (o == 15) W1t[row] = src[8];               // element k=128
}

// 256 thr / 4 waves; block = one 32-row n-tile x 32 latents (8 quad-iters).
// x staged once; quad loop is barrier-free; A from L2 per quad (small regs).
// grid 1024 = 4 blocks/CU; lhalf = bid>>9 keeps tile-sharing blocks on one XCD.
__global__ __launch_bounds__(256, 4)
void fused_mfma(const float* __restrict__ xg,
                const float* __restrict__ b1g, const float* __restrict__ W2g,
                const float* __restrict__ b2g,
                const unsigned short* __restrict__ W1f,
                const float* __restrict__ W1t,
                float* __restrict__ out_res, float* __restrict__ out_lad)
{
    __shared__ unsigned short sXh[34][72];   // x hi, stride 144B (16B-aligned)
    __shared__ unsigned short sXl[34][72];   // x lo
    __shared__ float sJ[32][4];              // per-wn partial logsums

    const int tid   = threadIdx.x;
    const int tile  = blockIdx.x & 511;      // 0..511 : 32-row n-tile
    const int lhalf = blockIdx.x >> 9;       // 0..1   : latent half
    const int pt    = tile >> 4;             // batch row
    const int s     = tile & 15;
    const size_t xrow0 = (size_t)pt * TROWS + s * 32;
    const size_t nbase = (size_t)tile * 32;

    // ---- stage x tile once: 34 rows x 64, bf16 hi/lo ----
    for (int i = tid; i < 34 * 16; i += 256) {
        const int row = i >> 4, c4 = (i & 15) << 2;
        const float4 v = *reinterpret_cast<const float4*>(
            xg + (xrow0 + row) * LATENT + c4);
        unsigned short h0,h1,h2,h3, l0,l1,l2,l3;
        bsplit(v.x, h0, l0); bsplit(v.y, h1, l1);
        bsplit(v.z, h2, l2); bsplit(v.w, h3, l3);
        *reinterpret_cast<US4*>(&sXh[row][c4]) = US4{h0, h1, h2, h3};
        *reinterpret_cast<US4*>(&sXl[row][c4]) = US4{l0, l1, l2, l3};
    }
    __syncthreads();   // single barrier; LDS read-only afterwards

    const int wn   = tid >> 6;               // 0..3
    const int lane = tid & 63;
    const int r32  = lane & 31;
    const int hi32 = lane >> 5;

    float jlog = 0.f, jprod = 1.f;

    #pragma unroll 1
    for (int q = 0; q < 8; ++q) {
        const int l = lhalf * 32 + q * 4 + wn;
        const unsigned short* A0 = W1f + (size_t)l * 16384 + (size_t)lane * 8;

        f32x16 acc[2];
        #pragma unroll
        for (int i = 0; i < 2; ++i)
            #pragma unroll
            for (int r = 0; r < 16; ++r) acc[i][r] = 0.f;

        // ---- K loop: A = W1 fragments (L2), B = x rows (LDS), j=1 ----
        #pragma unroll
        for (int ks = 0; ks < 8; ++ks) {
            const int lag = ks >> 2;
            const int cc  = (ks & 3) * 16 + hi32 * 8;
            const unsigned short* p0 = A0 + ks * 1024;
            bf16x8 awh[2], awl[2];
            #pragma unroll
            for (int i = 0; i < 2; ++i) {
                awh[i] = *reinterpret_cast<const bf16x8*>(p0 + i * 8192);
                awl[i] = *reinterpret_cast<const bf16x8*>(p0 + i * 8192 + 512);
            }
            const bf16x8 bxh = *reinterpret_cast<const bf16x8*>(&sXh[r32 + lag][cc]);
            const bf16x8 bxl = *reinterpret_cast<const bf16x8*>(&sXl[r32 + lag][cc]);
            #pragma unroll
            for (int i = 0; i < 2; ++i) {
                acc[i] = __builtin_amdgcn_mfma_f32_32x32x16_bf16(awh[i], bxh, acc[i], 0, 0, 0);
                acc[i] = __builtin_amdgcn_mfma_f32_32x32x16_bf16(awh[i], bxl, acc[i], 0, 0, 0);
                acc[i] = __builtin_amdgcn_mfma_f32_32x32x16_bf16(awl[i], bxh, acc[i], 0, 0, 0);
            }
        }

        // ---- epilogue: h in (i, g, m, hi32); n = r32 ----
        const float xt0 = xg[(xrow0 + 2 + r32) * LATENT + l];
        float res0 = 0.f, jp0 = 0.f, jc = 0.f;
        #pragma unroll
        for (int i = 0; i < 2; ++i)
            #pragma unroll
            for (int g = 0; g < 4; ++g) {
                const int h0 = l * HID + i * 32 + hi32 * 4 + g * 8;
                const f32x4 wt = *reinterpret_cast<const f32x4*>(W1t + h0);
                const f32x4 w2 = *reinterpret_cast<const f32x4*>(W2g + h0);
                const f32x4 b1 = *reinterpret_cast<const f32x4*>(b1g + h0);
                #pragma unroll
                for (int m = 0; m < 4; ++m) {
                    const float c0 = w2[m] * wt[m];
                    jc += c0;
                    const float pre0 = fmaf(xt0, wt[m], acc[i][g * 4 + m] + b1[m]);
                    res0 += w2[m] * fmaxf(pre0, SLOPE * pre0);
                    jp0 += (pre0 >= 0.f) ? c0 : 0.f;
                }
            }

        res0 += __shfl_xor(res0, 32);
        jp0  += __shfl_xor(jp0, 32);
        jc   += __shfl_xor(jc, 32);
        const float jac = SLOPE * jc + (1.f - SLOPE) * jp0;

        if (hi32 == 0)
            out_res[(nbase + r32) * LATENT + l] = res0 + b2g[l];

        jprod *= jac;
        if ((q & 3) == 3) {              // log every 4 quads (underflow-safe)
            jlog += logf(fabsf(jprod));
            jprod = 1.f;
        }
    }

    if (hi32 == 0) sJ[r32][wn] = jlog;
    __syncthreads();
    if (tid < 32) {
        const float part = sJ[tid][0] + sJ[tid][1] + sJ[tid][2] + sJ[tid][3];
        atomicAdd(&out_lad[nbase + tid], part);
    }
}

extern "C" void kernel_launch(void* const* d_in, const int* in_sizes, int n_in,
                              void* d_out, int out_size, void* d_ws, size_t ws_size,
                              hipStream_t stream) {
    const float* xg  = (const float*)d_in[0];
    const float* W1g = (const float*)d_in[1];
    const float* b1g = (const float*)d_in[2];
    const float* W2g = (const float*)d_in[3];
    const float* b2g = (const float*)d_in[4];

    float* out_res = (float*)d_out;
    float* out_lad = out_res + (size_t)NTOT * LATENT;

    float*          W1t = (float*)d_ws;                   // 16 KB
    unsigned short* W1f = (unsigned short*)(W1t + 4096);  // 2 MB fragment-major

    conv_w1<<<256, 256, 0, stream>>>(W1g, W1f, W1t, out_lad);

    dim3 grid(1024);  // 512 n-tiles x 2 latent halves = 4 blocks/CU
    fused_mfma<<<grid, 256, 0, stream>>>(xg, b1g, W2g, b2g, W1f, W1t,
                                         out_res, out_lad);
}